// Round 1
// 296.492 us; speedup vs baseline: 1.0264x; 1.0264x over previous
//
#include <hip/hip_runtime.h>

#define DIM 2048
#define NH 8
#define HD 256
#define NB 256
#define EPS 1e-5f

typedef short v8s __attribute__((ext_vector_type(8)));
typedef float v16f __attribute__((ext_vector_type(16)));

__device__ __forceinline__ short f2bf(float f) {
    union { float f; unsigned u; } c; c.f = f;
    unsigned u = c.u;
    unsigned r = (u + 0x7fffu + ((u >> 16) & 1u)) >> 16;
    return (short)r;
}

__device__ __forceinline__ float gelu_f(float x) {
    float u = 0.7978845608028654f * (x + 0.044715f * x * x * x);
    float t = 1.0f - 2.0f / (__expf(2.0f * u) + 1.0f);   // tanh(u)
    return 0.5f * x * (1.0f + t);
}

__device__ __forceinline__ float wave_sum(float v) {
#pragma unroll
    for (int m = 32; m >= 1; m >>= 1) v += __shfl_xor(v, m, 64);
    return v;
}

// ---------------- Kernel 1: mem pool + bf16 swizzle of A matrices -------------
// A swizzled layout: element (m=b, k=d) -> flat ((d>>4)*256 + b)*16 + (d&15)
// v2: 8 lanes per pooled row, 2 float4 each (128B-granule coalescing kept);
// shfl count per row 16 -> 3 (was 4 ds_swizzle per 16B -> LDS-pipe pressure).
__global__ __launch_bounds__(256) void prep_kernel(
    const float* __restrict__ mem, const float* __restrict__ f_ad,
    short* __restrict__ pooled_sw, short* __restrict__ fad_sw) {
    int blk = blockIdx.x, t = threadIdx.x;
    int q = t & 7;          // lane within 8-lane row group
    int rid = t >> 3;       // 0..31 row slot
#pragma unroll
    for (int it = 0; it < 8; ++it) {
        int r = blk * 256 + it * 32 + rid;               // row = b*2048 + d
        const float4* rp = (const float4*)mem + (size_t)r * 16 + q;
        float4 v0 = rp[0];
        float4 v1 = rp[8];
        float s = (v0.x + v0.y) + (v0.z + v0.w)
                + (v1.x + v1.y) + (v1.z + v1.w);
        s += __shfl_xor(s, 1); s += __shfl_xor(s, 2); s += __shfl_xor(s, 4);
        if (q == 0) {
            int d = r & 2047, b = r >> 11;
            pooled_sw[((size_t)(d >> 4) * NB + b) * 16 + (d & 15)] = f2bf(s * 0.015625f);
        }
    }
    int idx = blk * 256 + t;
    int b = idx >> 11, d = idx & 2047;
    fad_sw[((size_t)(d >> 4) * NB + b) * 16 + (d & 15)] = f2bf(f_ad[idx]);
}

// ---------------- Kernel 2: two NT GEMMs (bf16 MFMA) --------------------------
// C[m][n] = sum_k A[m][k] * W[n][k].  M=256 (full), N-tile=32, BK=128.
// v2: (a) LDS B-tile layout interleaved: idx16 = K0*64 + row*2 + half
//     -> both ds_write (staging) and ds_read (frag) spread 8 lanes per
//        bank-octet (was 16-way conflict on the write side: bank=row*4%32,
//        rows 0..3 per wave).
//     (b) double-buffered sB -> ONE barrier per K-step (was 2). Iter i writes
//        sB[i&1], barriers, reads sB[i&1]; the i+2 write of the same buffer is
//        separated from the i-th read by the i+1 barrier -> race-free.
__global__ __launch_bounds__(512) void gemm_kernel(
    const short* __restrict__ pooled_sw, const short* __restrict__ fad_sw,
    const float* __restrict__ k1_W, const float* __restrict__ qv_W,
    float* __restrict__ k1_out, float* __restrict__ qv_out) {
    __shared__ short sB[2][8 * 64 * 8];   // 2 x 8KB
    int blk = blockIdx.x;
    const short* A; const float* W; float* C; int ldC, n0;
    if (blk < 64) { A = pooled_sw; W = k1_W; C = k1_out; ldC = 2048; n0 = blk * 32; }
    else          { A = fad_sw;    W = qv_W; C = qv_out; ldC = 4096; n0 = (blk - 64) * 32; }
    int t = threadIdx.x;
    int lane = t & 63, w = t >> 6;           // 8 waves, wave w -> rows 32w..32w+31
    int row = t >> 4;                        // 0..31  (B staging n-row)
    int c8 = t & 15;                         // 0..15  (B staging k-chunk of 8)
    const float* wp = W + (size_t)(n0 + row) * 2048 + c8 * 8;
    float4 b0 = *(const float4*)(wp);
    float4 b1 = *(const float4*)(wp + 4);
    v16f acc;
#pragma unroll
    for (int r = 0; r < 16; ++r) acc[r] = 0.f;
    // A frag: lane l of wave w -> m = w*32+(l&31), k = K0*16+(l>>5)*8+j
    const short* Abase = A + (size_t)(w * 32 + (lane & 31)) * 16 + (lane >> 5) * 8;
    // staging dest: K0local = c8>>1, half = c8&1 -> idx16 = K0*64 + row*2 + half
    int bidx = ((c8 >> 1) * 64 + row * 2 + (c8 & 1)) * 8;
    // frag read: lane l wants (k0, n=l&31, half=l>>5)
    int ridx_base = ((lane & 31) * 2 + (lane >> 5)) * 8;
    for (int iter = 0; iter < 16; ++iter) {
        short* sp = sB[iter & 1];
        v8s bb;
        bb[0] = f2bf(b0.x); bb[1] = f2bf(b0.y); bb[2] = f2bf(b0.z); bb[3] = f2bf(b0.w);
        bb[4] = f2bf(b1.x); bb[5] = f2bf(b1.y); bb[6] = f2bf(b1.z); bb[7] = f2bf(b1.w);
        *(v8s*)(sp + bidx) = bb;
        if (iter + 1 < 16) {                 // issue next-B before the barrier:
            b0 = *(const float4*)(wp + (iter + 1) * 128);   // latency spans the
            b1 = *(const float4*)(wp + (iter + 1) * 128 + 4); // barrier + MFMAs
        }
        __syncthreads();                     // staged tile visible
#pragma unroll
        for (int k0 = 0; k0 < 8; ++k0) {
            int K0 = iter * 8 + k0;
            v8s afrag = *(const v8s*)(Abase + (size_t)K0 * 4096);
            v8s bfrag = *(const v8s*)(sp + k0 * 512 + ridx_base);
            acc = __builtin_amdgcn_mfma_f32_32x32x16_bf16(afrag, bfrag, acc, 0, 0, 0);
        }
    }
#pragma unroll
    for (int r = 0; r < 16; ++r) {
        int rr = (r & 3) + 8 * (r >> 2) + 4 * (lane >> 5);
        int m = w * 32 + rr;
        C[(size_t)m * ldC + n0 + (lane & 31)] = acc[r];
    }
}

// ---------------- Kernel 3: epilogue (one block per batch element) ------------
__device__ void ln_heads(float* buf, const float* sLnw, const float* sLnb, float* sTmp) {
    int t = threadIdx.x; int h = t >> 5, i = t & 31;
    float s = 0.f, ss = 0.f;
#pragma unroll
    for (int j = 0; j < 8; ++j) { float x = buf[h * HD + i + 32 * j]; s += x; ss += x * x; }
#pragma unroll
    for (int m = 16; m >= 1; m >>= 1) { s += __shfl_xor(s, m, 64); ss += __shfl_xor(ss, m, 64); }
    if (i == 0) {
        float mu = s * (1.0f / HD);
        float var = ss * (1.0f / HD) - mu * mu;
        sTmp[h * 2] = mu; sTmp[h * 2 + 1] = rsqrtf(var + EPS);
    }
    __syncthreads();
    float mu = sTmp[h * 2], rs = sTmp[h * 2 + 1];
#pragma unroll
    for (int j = 0; j < 8; ++j) {
        int dd = i + 32 * j; int idx = h * HD + dd;
        buf[idx] = (buf[idx] - mu) * rs * sLnw[dd] + sLnb[dd];
    }
    __syncthreads();
}

__global__ __launch_bounds__(256) void epilogue_kernel(
    const float* __restrict__ qv_out, const float* __restrict__ k1_out,
    const float* __restrict__ f_age, const float* __restrict__ age_gap,
    const float* __restrict__ ln_w, const float* __restrict__ ln_b,
    const float* __restrict__ ln2_w, const float* __restrict__ ln2_b,
    const float* __restrict__ rW, const float* __restrict__ rb,
    const float* __restrict__ eW, const float* __restrict__ eb,
    const float* __restrict__ cw1, const float* __restrict__ cw2,
    float* __restrict__ out) {
    __shared__ float sQ[DIM], sK1[DIM], sK2[DIM], sV[DIM], sO1[DIM], sO2[DIM];
    __shared__ float sLnw[HD], sLnb[HD];
    __shared__ float sCW1[192], sCW2[192];
    __shared__ float sSc[2][NH][NH];
    __shared__ float sStats[32];
    int b = blockIdx.x, t = threadIdx.x;
    int wv = t >> 6;
    sLnw[t & 255] = ln_w[t & 255];
    sLnb[t & 255] = ln_b[t & 255];
    if (t < 192) { sCW1[t] = cw1[t]; sCW2[t] = cw2[t]; }
    const float4* qv4 = (const float4*)(qv_out + (size_t)b * 4096);
    const float4* k14 = (const float4*)(k1_out + (size_t)b * DIM);
    const float4* fa4 = (const float4*)(f_age + (size_t)b * DIM);
    const float4* rW4 = (const float4*)rW;
    float4* sQ4 = (float4*)sQ; float4* sV4 = (float4*)sV;
    float4* sK14 = (float4*)sK1; float4* sK24 = (float4*)sK2;
    float dotp = 0.f;
#pragma unroll
    for (int j = 0; j < 2; ++j) {
        int idx = t + 256 * j;
        sQ4[idx] = qv4[idx];
        sV4[idx] = qv4[512 + idx];
        sK14[idx] = k14[idx];
        float4 fa = fa4[idx];
        sK24[idx] = fa;
        float4 rw = rW4[idx];
        dotp += fa.x * rw.x + fa.y * rw.y + fa.z * rw.z + fa.w * rw.w;
    }
    dotp = wave_sum(dotp);
    if ((t & 63) == 0) sStats[wv] = dotp;
    __syncthreads();
    float red = sStats[0] + sStats[1] + sStats[2] + sStats[3] + rb[0];
    float gap = age_gap[b];
#pragma unroll
    for (int j = 0; j < 8; ++j) {
        int idx = t + 256 * j;
        float2 e2 = ((const float2*)eW)[idx];
        sK2[idx] += red * e2.x + gap * e2.y + eb[idx];
    }
    __syncthreads();
    ln_heads(sQ, sLnw, sLnb, sStats);
    ln_heads(sK1, sLnw, sLnb, sStats);
    ln_heads(sK2, sLnw, sLnb, sStats);
    // ---- attention scores (both attns): group of 16 threads per (attn, qi)
    {
        int g = t >> 4, l16 = t & 15;
        int at = g >> 3, qi = g & 7;
        const float* kb = at ? sK2 : sK1;
        float acc[8];
#pragma unroll
        for (int j = 0; j < 8; ++j) acc[j] = 0.f;
        for (int ii = 0; ii < 16; ++ii) {
            int d = l16 + 16 * ii;
            float qd = sQ[qi * HD + d];
#pragma unroll
            for (int j = 0; j < 8; ++j) acc[j] += qd * kb[j * HD + d];
        }
#pragma unroll
        for (int m = 8; m >= 1; m >>= 1)
#pragma unroll
            for (int j = 0; j < 8; ++j) acc[j] += __shfl_xor(acc[j], m, 64);
        if (l16 == 0) {
#pragma unroll
            for (int j = 0; j < 8; ++j) sSc[at][qi][j] = acc[j] * (1.0f / 16.0f);
        }
    }
    __syncthreads();
    if (t < 16) {
        int at = t >> 3, qi = t & 7;
        float mx = -1e30f;
#pragma unroll
        for (int j = 0; j < 8; ++j) mx = fmaxf(mx, sSc[at][qi][j]);
        float e[8], sum = 0.f;
#pragma unroll
        for (int j = 0; j < 8; ++j) { e[j] = __expf(sSc[at][qi][j] - mx); sum += e[j]; }
        float inv = 1.0f / sum;
#pragma unroll
        for (int j = 0; j < 8; ++j) sSc[at][qi][j] = e[j] * inv;
    }
    __syncthreads();
    // ---- P @ V for both attentions
    {
        int qi = t >> 5, i32 = t & 31;
#pragma unroll
        for (int jd = 0; jd < 8; ++jd) {
            int d = i32 + 32 * jd;
            float o1 = 0.f, o2 = 0.f;
#pragma unroll
            for (int j = 0; j < 8; ++j) {
                float vv = sV[j * HD + d];
                o1 += sSc[0][qi][j] * vv;
                o2 += sSc[1][qi][j] * vv;
            }
            sO1[qi * HD + d] = o1;
            sO2[qi * HD + d] = o2;
        }
    }
    __syncthreads();
    // ---- conv1d (channels=8, k=3, pad=1) on both
    {
        int o = t >> 5, i32 = t & 31;
        float w1r[24], w2r[24];
#pragma unroll
        for (int ic = 0; ic < 8; ++ic)
#pragma unroll
            for (int tp = 0; tp < 3; ++tp) {
                w1r[ic * 3 + tp] = sCW1[(o * 8 + ic) * 3 + tp];
                w2r[ic * 3 + tp] = sCW2[(o * 8 + ic) * 3 + tp];
            }
        float r1[8], r2[8];
#pragma unroll
        for (int jd = 0; jd < 8; ++jd) {
            int l = i32 + 32 * jd;
            float a1 = 0.f, a2 = 0.f;
#pragma unroll
            for (int ic = 0; ic < 8; ++ic) {
                float xm1 = (l > 0)   ? sO1[ic * HD + l - 1] : 0.f;
                float x01 =             sO1[ic * HD + l];
                float xp1 = (l < 255) ? sO1[ic * HD + l + 1] : 0.f;
                a1 += xm1 * w1r[ic * 3] + x01 * w1r[ic * 3 + 1] + xp1 * w1r[ic * 3 + 2];
                float xm2 = (l > 0)   ? sO2[ic * HD + l - 1] : 0.f;
                float x02 =             sO2[ic * HD + l];
                float xp2 = (l < 255) ? sO2[ic * HD + l + 1] : 0.f;
                a2 += xm2 * w2r[ic * 3] + x02 * w2r[ic * 3 + 1] + xp2 * w2r[ic * 3 + 2];
            }
            r1[jd] = a1; r2[jd] = a2;
        }
        __syncthreads();
#pragma unroll
        for (int jd = 0; jd < 8; ++jd) {
            int l = i32 + 32 * jd;
            sO1[o * HD + l] = r1[jd];
            sO2[o * HD + l] = r2[jd];
        }
    }
    __syncthreads();
    ln_heads(sO1, sLnw, sLnb, sStats);
    ln_heads(sO2, sLnw, sLnb, sStats);
#pragma unroll
    for (int j = 0; j < 8; ++j) {
        int idx = t + 256 * j;
        sO1[idx] = sO1[idx] + sO2[idx] + sV[idx];
    }
    __syncthreads();
    ln_heads(sO1, sLnw, sLnb, sStats);
#pragma unroll
    for (int j = 0; j < 8; ++j) {
        int idx = t + 256 * j;
        sO1[idx] = gelu_f(sO1[idx]);
    }
    // final LN over 2048 + gelu (ownership t+256j matches gelu loop)
    float s = 0.f, ss = 0.f;
#pragma unroll
    for (int j = 0; j < 8; ++j) { float x = sO1[t + 256 * j]; s += x; ss += x * x; }
    s = wave_sum(s); ss = wave_sum(ss);
    if ((t & 63) == 0) { sStats[wv] = s; sStats[8 + wv] = ss; }
    __syncthreads();
    float S  = sStats[0] + sStats[1] + sStats[2] + sStats[3];
    float SS = sStats[8] + sStats[9] + sStats[10] + sStats[11];
    float mu = S * (1.0f / DIM);
    float var = SS * (1.0f / DIM) - mu * mu;
    float rs = rsqrtf(var + EPS);
    float* ob = out + (size_t)b * DIM;
#pragma unroll
    for (int j = 0; j < 8; ++j) {
        int idx = t + 256 * j;
        float val = (sO1[idx] - mu) * rs * ln2_w[idx] + ln2_b[idx];
        ob[idx] = gelu_f(val);
    }
}

extern "C" void kernel_launch(void* const* d_in, const int* in_sizes, int n_in,
                              void* d_out, int out_size, void* d_ws, size_t ws_size,
                              hipStream_t stream) {
    const float* f_ad    = (const float*)d_in[0];
    const float* f_age   = (const float*)d_in[1];
    const float* mem     = (const float*)d_in[2];
    const float* age_gap = (const float*)d_in[3];
    const float* qv_W    = (const float*)d_in[4];
    const float* k1_W    = (const float*)d_in[5];
    // d_in[6] = k2_W: dead in the reference (never applied)
    const float* ln_w    = (const float*)d_in[7];
    const float* ln_b    = (const float*)d_in[8];
    const float* ln2_w   = (const float*)d_in[9];
    const float* ln2_b   = (const float*)d_in[10];
    const float* rW      = (const float*)d_in[11];
    const float* rb      = (const float*)d_in[12];
    const float* eW      = (const float*)d_in[13];
    const float* eb      = (const float*)d_in[14];
    const float* cw1     = (const float*)d_in[15];
    const float* cw2     = (const float*)d_in[16];
    float* out = (float*)d_out;
    char* ws = (char*)d_ws;
    short* pooled_sw = (short*)ws;                       // 1 MB
    short* fad_sw    = (short*)(ws + (1 << 20));         // 1 MB
    float* k1_out    = (float*)(ws + (2 << 20));         // 2 MB
    float* qv_out    = (float*)(ws + (4 << 20));         // 4 MB
    prep_kernel<<<2048, 256, 0, stream>>>(mem, f_ad, pooled_sw, fad_sw);
    gemm_kernel<<<192, 512, 0, stream>>>(pooled_sw, fad_sw, k1_W, qv_W, k1_out, qv_out);
    epilogue_kernel<<<256, 256, 0, stream>>>(qv_out, k1_out, f_age, age_gap,
                                             ln_w, ln_b, ln2_w, ln2_b,
                                             rW, rb, eW, eb, cw1, cw2, out);
}